// Round 1
// baseline (978.984 us; speedup 1.0000x reference)
//
#include <hip/hip_runtime.h>
#include <hip/hip_bf16.h>
#include <stdint.h>

#define S_N 10000
#define MPAD 10112
#define B_N 2048
#define F_N 128

typedef __bf16 bf16x8 __attribute__((ext_vector_type(8)));
typedef float  f32x4  __attribute__((ext_vector_type(4)));
typedef unsigned long long u64;
typedef unsigned int u32;
typedef unsigned short u16;

union Bf8 { u16 us[8]; bf16x8 v; };

__device__ __forceinline__ float lrelu02(float x) { return x >= 0.0f ? x : 0.2f * x; }
__device__ __forceinline__ float eluf(float x)    { return x > 0.0f ? x : expm1f(x); }

// ---------------- K1: adjacency gather -> popcounts + bit-transposed masks ----------------
// grid (20 s-chunks, 32 b-words, 2 matrices), block 256
__global__ __launch_bounds__(256) void k_bits(const int* __restrict__ adj_c,
        const int* __restrict__ adj_p, const int* __restrict__ src,
        u64* __restrict__ tcity, u64* __restrict__ tprov,
        u32* __restrict__ cc, u32* __restrict__ pc) {
    const int sc = blockIdx.x, wb = blockIdx.y, mat = blockIdx.z;
    const int t = threadIdx.x, l = t & 63, w = t >> 6;
    const int* adj = mat ? adj_p : adj_c;
    u64* tb = mat ? tprov : tcity;
    u32* cnt = mat ? pc : cc;
    __shared__ u64 wt[64][8];
    __shared__ u32 lc[64];
    if (t < 64) lc[t] = 0;
    __syncthreads();
    const int s1 = sc * 512 + t;
    const int s2 = s1 + 256;
    for (int bb = 0; bb < 64; ++bb) {
        int row = src[wb * 64 + bb];
        const int* rp = adj + (size_t)row * S_N;
        int v1 = (s1 < S_N) ? rp[s1] : 0;
        int v2 = (s2 < S_N) ? rp[s2] : 0;
        u64 b1 = __ballot(v1 > 0);
        u64 b2 = __ballot(v2 > 0);
        if (l == 0) {
            wt[bb][w] = b1;
            wt[bb][w + 4] = b2;
            atomicAdd(&lc[bb], (u32)(__popcll(b1) + __popcll(b2)));
        }
    }
    __syncthreads();
    if (t < 64) atomicAdd(&cnt[wb * 64 + t], lc[t]);
    // bit-transpose each 64x64 tile: out word for s has bit (b&63)
    for (int tile = w; tile < 8; tile += 4) {
        u64 wv = wt[l][tile];
        u64 myw = 0;
        #pragma unroll
        for (int j = 0; j < 64; ++j) {
            u64 bal = __ballot((int)((wv >> j) & 1ull));
            if (l == j) myw = bal;
        }
        int s = sc * 512 + tile * 64 + l;
        if (s < MPAD) tb[(size_t)wb * MPAD + s] = myw;
    }
}

// ---------------- K2a: Y^T/Z^T = (Sfeat[src]/count)^T in bf16 ----------------
__global__ __launch_bounds__(256) void k_yz(const float* __restrict__ Sfeat,
        const int* __restrict__ src, const u32* __restrict__ cc, const u32* __restrict__ pc,
        __bf16* __restrict__ YT, __bf16* __restrict__ ZT) {
    int idx = blockIdx.x * 256 + threadIdx.x; // 128*2048
    int f = idx >> 11, b = idx & 2047;
    float sv = Sfeat[src[b] * F_N + f];
    float icc = cc[b] ? 1.0f / (float)cc[b] : 0.0f;
    float ipc = pc[b] ? 1.0f / (float)pc[b] : 0.0f;
    YT[f * B_N + b] = (__bf16)(sv * icc);
    ZT[f * B_N + b] = (__bf16)(sv * ipc);
}

// ---------------- K2b: Sfeat -> bf16 (padded rows zero) ----------------
__global__ __launch_bounds__(256) void k_sfb(const float* __restrict__ Sfeat, __bf16* __restrict__ SfB) {
    int i = blockIdx.x * 256 + threadIdx.x; // MPAD*128
    int s = i >> 7;
    SfB[i] = (__bf16)(s < S_N ? Sfeat[i] : 0.0f);
}

// ---------------- K2c: W2T bf16, h1T bf16 (K padded to 32 with zeros), q ----------------
__global__ __launch_bounds__(128) void k_small(const float* __restrict__ Rfeat,
        const float* __restrict__ W1, const float* __restrict__ W2, const float* __restrict__ a,
        __bf16* __restrict__ W2T, __bf16* __restrict__ h1T, float* __restrict__ q) {
    __shared__ float red[128];
    int bid = blockIdx.x, t = threadIdx.x;
    if (bid < 64) {
        int h = bid >> 4, r = bid & 15;
        float hv = 0.0f;
        const float* rf = Rfeat + r * F_N;
        const float* wp = W1 + h * F_N * F_N + t;
        for (int k = 0; k < F_N; ++k) hv += rf[k] * wp[k * F_N];
        h1T[(h * F_N + t) * 32 + r] = (__bf16)hv;
        h1T[(h * F_N + t) * 32 + 16 + r] = (__bf16)0.0f;
        red[t] = hv * a[h * 256 + t];   // a[:F]
        __syncthreads();
        for (int off = 64; off > 0; off >>= 1) {
            if (t < off) red[t] += red[t + off];
            __syncthreads();
        }
        if (t == 0) q[h * 16 + r] = red[0];
    } else {
        int idx = (bid - 64) * 128 + t; // 0..65535
        int hn = idx >> 7, k = idx & 127;
        int h = hn >> 7, n = hn & 127;
        W2T[idx] = (__bf16)W2[(h * F_N + k) * F_N + n];
    }
}

// ---------------- G1: T = Cm^T*Y + Pm^T*Z via MFMA (computes T^T, stores to T[s][f]) ----------------
// grid (79 s-tiles, 8 k-splits), block 256
__global__ __launch_bounds__(256) void g_T(const __bf16* __restrict__ YT, const __bf16* __restrict__ ZT,
        const u64* __restrict__ tcity, const u64* __restrict__ tprov, float* __restrict__ T) {
    const int t = threadIdx.x, l = t & 63, w = t >> 6;
    const int wm = w >> 1, wn = w & 1;
    const int quad = l >> 4, ln = l & 15;
    const int s_blk = blockIdx.x * 128;
    const unsigned char* cb = (const unsigned char*)tcity;
    const unsigned char* pb = (const unsigned char*)tprov;
    const f32x4 fz = {0.0f, 0.0f, 0.0f, 0.0f};
    f32x4 acc[4][4];
    #pragma unroll
    for (int mt = 0; mt < 4; ++mt)
        #pragma unroll
        for (int nt = 0; nt < 4; ++nt) acc[mt][nt] = fz;
    const int k_base = blockIdx.y * 256;
    for (int it = 0; it < 8; ++it) {
        int kk = k_base + it * 32;
        bf16x8 Ya[4], Za[4];
        #pragma unroll
        for (int mt = 0; mt < 4; ++mt) {
            int f = wm * 64 + mt * 16 + ln;
            Ya[mt] = *(const bf16x8*)(YT + f * B_N + kk + quad * 8);
            Za[mt] = *(const bf16x8*)(ZT + f * B_N + kk + quad * 8);
        }
        bf16x8 Bc[4], Bp[4];
        #pragma unroll
        for (int nt = 0; nt < 4; ++nt) {
            int s = s_blk + wn * 64 + nt * 16 + ln;
            size_t base = ((size_t)(kk >> 6) * MPAD + s) * 8 + ((kk >> 3) & 7) + quad;
            unsigned int cby = cb[base], pby = pb[base];
            Bf8 uc, up;
            #pragma unroll
            for (int j = 0; j < 8; ++j) {
                uc.us[j] = ((cby >> j) & 1u) ? (u16)0x3F80 : (u16)0;
                up.us[j] = ((pby >> j) & 1u) ? (u16)0x3F80 : (u16)0;
            }
            Bc[nt] = uc.v; Bp[nt] = up.v;
        }
        #pragma unroll
        for (int mt = 0; mt < 4; ++mt)
            #pragma unroll
            for (int nt = 0; nt < 4; ++nt) {
                acc[mt][nt] = __builtin_amdgcn_mfma_f32_16x16x32_bf16(Ya[mt], Bc[nt], acc[mt][nt], 0, 0, 0);
                acc[mt][nt] = __builtin_amdgcn_mfma_f32_16x16x32_bf16(Za[mt], Bp[nt], acc[mt][nt], 0, 0, 0);
            }
    }
    // D rows = f (quad*4+reg), cols = s (ln)
    #pragma unroll
    for (int nt = 0; nt < 4; ++nt) {
        int s = s_blk + wn * 64 + nt * 16 + ln;
        if (s < S_N) {
            #pragma unroll
            for (int mt = 0; mt < 4; ++mt) {
                int f0 = wm * 64 + mt * 16 + quad * 4;
                #pragma unroll
                for (int r = 0; r < 4; ++r)
                    atomicAdd(&T[(size_t)s * F_N + f0 + r], acc[mt][nt][r]);
            }
        }
    }
}

// ---------------- K4: T -> bf16 ----------------
__global__ __launch_bounds__(256) void k_tconv(const float* __restrict__ T, __bf16* __restrict__ Tb) {
    int i = blockIdx.x * 256 + threadIdx.x;
    Tb[i] = (__bf16)T[i];
}

// ---------------- G2: h2[h] = Sfeat @ W2[h]  (grid 79 x 4) ----------------
__global__ __launch_bounds__(256) void g_h2(const __bf16* __restrict__ A, const __bf16* __restrict__ W2T,
        float* __restrict__ h2) {
    const int t = threadIdx.x, l = t & 63, w = t >> 6;
    const int wm = w >> 1, wn = w & 1, quad = l >> 4, ln = l & 15;
    const int s0 = blockIdx.x * 128, h = blockIdx.y;
    const f32x4 fz = {0.0f, 0.0f, 0.0f, 0.0f};
    f32x4 acc[4][4];
    #pragma unroll
    for (int mt = 0; mt < 4; ++mt)
        #pragma unroll
        for (int nt = 0; nt < 4; ++nt) acc[mt][nt] = fz;
    #pragma unroll
    for (int it = 0; it < 4; ++it) {
        int kk = it * 32;
        bf16x8 af[4], bfr[4];
        #pragma unroll
        for (int mt = 0; mt < 4; ++mt)
            af[mt] = *(const bf16x8*)(A + (size_t)(s0 + wm * 64 + mt * 16 + ln) * F_N + kk + quad * 8);
        #pragma unroll
        for (int nt = 0; nt < 4; ++nt)
            bfr[nt] = *(const bf16x8*)(W2T + (size_t)(h * F_N + wn * 64 + nt * 16 + ln) * F_N + kk + quad * 8);
        #pragma unroll
        for (int mt = 0; mt < 4; ++mt)
            #pragma unroll
            for (int nt = 0; nt < 4; ++nt)
                acc[mt][nt] = __builtin_amdgcn_mfma_f32_16x16x32_bf16(af[mt], bfr[nt], acc[mt][nt], 0, 0, 0);
    }
    #pragma unroll
    for (int mt = 0; mt < 4; ++mt)
        #pragma unroll
        for (int nt = 0; nt < 4; ++nt) {
            int f = wn * 64 + nt * 16 + ln;
            #pragma unroll
            for (int r = 0; r < 4; ++r) {
                int s = s0 + wm * 64 + mt * 16 + quad * 4 + r;
                h2[((size_t)h * MPAD + s) * F_N + f] = acc[mt][nt][r];
            }
        }
}

// ---------------- K5: per-row inter-attention softmax ----------------
__global__ __launch_bounds__(64) void k_att(const float* __restrict__ h2, const float* __restrict__ a,
        const float* __restrict__ q, const int* __restrict__ inter,
        float* __restrict__ att, __bf16* __restrict__ attb) {
    const int s = blockIdx.x, l = threadIdx.x;
    if (s >= S_N) {
        if (l < 16) {
            for (int h = 0; h < 4; ++h) {
                att[((size_t)h * MPAD + s) * 16 + l] = 0.0f;
                attb[((size_t)h * MPAD + s) * 16 + l] = (__bf16)0.0f;
            }
        }
        return;
    }
    float p[4];
    #pragma unroll
    for (int h = 0; h < 4; ++h) {
        const float* hp = h2 + ((size_t)h * MPAD + s) * F_N;
        float v = hp[l] * a[h * 256 + 128 + l] + hp[64 + l] * a[h * 256 + 192 + l];
        #pragma unroll
        for (int m = 32; m > 0; m >>= 1) v += __shfl_xor(v, m, 64);
        p[h] = v;
    }
    if (l < 16) {
        int msk = inter[s * 16 + l] > 0;
        int cn = msk;
        #pragma unroll
        for (int m = 8; m > 0; m >>= 1) cn += __shfl_xor(cn, m, 16);
        #pragma unroll
        for (int h = 0; h < 4; ++h) {
            float e = lrelu02(p[h] + q[h * 16 + l]);
            float me = msk ? e : -3e38f;
            #pragma unroll
            for (int m = 8; m > 0; m >>= 1) me = fmaxf(me, __shfl_xor(me, m, 16));
            float ex = msk ? expf(e - me) : 0.0f;
            float sm = ex;
            #pragma unroll
            for (int m = 8; m > 0; m >>= 1) sm += __shfl_xor(sm, m, 16);
            float av = cn > 0 ? ex / sm : 0.0625f;
            att[((size_t)h * MPAD + s) * 16 + l] = av;
            attb[((size_t)h * MPAD + s) * 16 + l] = (__bf16)av;
        }
    }
}

// ---------------- G3: P[h] = T @ W2[h] + att[h] @ h1[h], + BN column sums ----------------
__global__ __launch_bounds__(256) void g_P(const __bf16* __restrict__ Tb, const __bf16* __restrict__ W2T,
        const __bf16* __restrict__ attb, const __bf16* __restrict__ h1T,
        float* __restrict__ P, float* __restrict__ usum, float* __restrict__ usq) {
    const int t = threadIdx.x, l = t & 63, w = t >> 6;
    const int wm = w >> 1, wn = w & 1, quad = l >> 4, ln = l & 15;
    const int s0 = blockIdx.x * 128, h = blockIdx.y;
    const f32x4 fz = {0.0f, 0.0f, 0.0f, 0.0f};
    f32x4 acc[4][4];
    #pragma unroll
    for (int mt = 0; mt < 4; ++mt)
        #pragma unroll
        for (int nt = 0; nt < 4; ++nt) acc[mt][nt] = fz;
    // att @ h1 : K=16 padded to 32 (padding region is zero on both sides)
    {
        bf16x8 a2[4], b2[4];
        #pragma unroll
        for (int mt = 0; mt < 4; ++mt) {
            int s = s0 + wm * 64 + mt * 16 + ln;
            Bf8 az;
            az.v = *(const bf16x8*)(attb + ((size_t)h * MPAD + s) * 16 + (quad & 1) * 8);
            if (quad >= 2) {
                #pragma unroll
                for (int j = 0; j < 8; ++j) az.us[j] = 0;
            }
            a2[mt] = az.v;
        }
        #pragma unroll
        for (int nt = 0; nt < 4; ++nt) {
            int f = wn * 64 + nt * 16 + ln;
            b2[nt] = *(const bf16x8*)(h1T + ((size_t)(h * F_N + f)) * 32 + quad * 8);
        }
        #pragma unroll
        for (int mt = 0; mt < 4; ++mt)
            #pragma unroll
            for (int nt = 0; nt < 4; ++nt)
                acc[mt][nt] = __builtin_amdgcn_mfma_f32_16x16x32_bf16(a2[mt], b2[nt], acc[mt][nt], 0, 0, 0);
    }
    #pragma unroll
    for (int it = 0; it < 4; ++it) {
        int kk = it * 32;
        bf16x8 af[4], bfr[4];
        #pragma unroll
        for (int mt = 0; mt < 4; ++mt)
            af[mt] = *(const bf16x8*)(Tb + (size_t)(s0 + wm * 64 + mt * 16 + ln) * F_N + kk + quad * 8);
        #pragma unroll
        for (int nt = 0; nt < 4; ++nt)
            bfr[nt] = *(const bf16x8*)(W2T + (size_t)(h * F_N + wn * 64 + nt * 16 + ln) * F_N + kk + quad * 8);
        #pragma unroll
        for (int mt = 0; mt < 4; ++mt)
            #pragma unroll
            for (int nt = 0; nt < 4; ++nt)
                acc[mt][nt] = __builtin_amdgcn_mfma_f32_16x16x32_bf16(af[mt], bfr[nt], acc[mt][nt], 0, 0, 0);
    }
    __shared__ float lsum[128], lsq[128];
    if (t < 128) { lsum[t] = 0.0f; lsq[t] = 0.0f; }
    __syncthreads();
    #pragma unroll
    for (int nt = 0; nt < 4; ++nt) {
        int f = wn * 64 + nt * 16 + ln;
        float p1 = 0.0f, p2 = 0.0f;
        #pragma unroll
        for (int mt = 0; mt < 4; ++mt) {
            int sb = s0 + wm * 64 + mt * 16 + quad * 4;
            #pragma unroll
            for (int r = 0; r < 4; ++r) {
                float val = acc[mt][nt][r];
                P[((size_t)h * MPAD + sb + r) * F_N + f] = val;
                p1 += val; p2 += val * val;
            }
        }
        atomicAdd(&lsum[f], p1);
        atomicAdd(&lsq[f], p2);
    }
    __syncthreads();
    if (t < 128) {
        atomicAdd(&usum[h * F_N + t], lsum[t]);
        atomicAdd(&usq[h * F_N + t], lsq[t]);
    }
}

// ---------------- K6: M[h] = att[h]^T @ h2[h] (partial, atomics) ----------------
__global__ __launch_bounds__(128) void k_M(const float* __restrict__ att, const float* __restrict__ h2,
        float* __restrict__ M) {
    const int h = blockIdx.y, t = threadIdx.x;
    const int s0 = blockIdx.x * 200;
    float acc[16] = {};
    for (int s = s0; s < s0 + 200; ++s) {
        float hv = h2[((size_t)h * MPAD + s) * F_N + t];
        const float* ar = att + ((size_t)h * MPAD + s) * 16;
        #pragma unroll
        for (int r = 0; r < 16; ++r) acc[r] += ar[r] * hv;
    }
    #pragma unroll
    for (int r = 0; r < 16; ++r) atomicAdd(&M[(h * 16 + r) * F_N + t], acc[r]);
}

// ---------------- K7: BN finalize (u params) + v = lrelu(bn1(M)) ----------------
__global__ __launch_bounds__(128) void k_bn(const float* __restrict__ usum, const float* __restrict__ usq,
        const float* __restrict__ M, const float* __restrict__ g1, const float* __restrict__ b1,
        const float* __restrict__ g2, const float* __restrict__ b2,
        float* __restrict__ scale_u, float* __restrict__ shift_u, __bf16* __restrict__ vb) {
    const int h = blockIdx.x, f = threadIdx.x;
    const int i = h * F_N + f;
    float mean = usum[i] * (1.0f / S_N);
    float var = usq[i] * (1.0f / S_N) - mean * mean;
    float sc = g2[i] * rsqrtf(var + 1e-5f);
    scale_u[i] = sc;
    shift_u[i] = b2[i] - mean * sc;
    float mv[16], s1 = 0.0f, s2 = 0.0f;
    #pragma unroll
    for (int r = 0; r < 16; ++r) {
        mv[r] = M[(h * 16 + r) * F_N + f];
        s1 += mv[r]; s2 += mv[r] * mv[r];
    }
    float m1 = s1 * 0.0625f, v1 = s2 * 0.0625f - m1 * m1;
    float g = g1[i] * rsqrtf(v1 + 1e-5f);
    float bb = b1[i] - m1 * g;
    #pragma unroll
    for (int r = 0; r < 16; ++r)
        vb[(h * 16 + r) * F_N + f] = (__bf16)lrelu02(mv[r] * g + bb);
}

// ---------------- K7b: u = lrelu(bn2(P)) in bf16 ----------------
__global__ __launch_bounds__(256) void k_u(const float* __restrict__ P, const float* __restrict__ scale_u,
        const float* __restrict__ shift_u, __bf16* __restrict__ ub) {
    int i = blockIdx.x * 256 + threadIdx.x;  // 4*MPAD*128
    int f = i & 127;
    int h = i / (MPAD * F_N);
    float val = P[i] * scale_u[h * F_N + f] + shift_u[h * F_N + f];
    ub[i] = (__bf16)lrelu02(val);
}

// ---------------- G4: G[s][h*16+r] = elu(u[h] @ v[h]^T) ----------------
__global__ __launch_bounds__(128) void g_G(const __bf16* __restrict__ ub, const __bf16* __restrict__ vb,
        float* __restrict__ G) {
    const int t = threadIdx.x, l = t & 63, w = t >> 6;
    const int quad = l >> 4, ln = l & 15;
    const int s0 = blockIdx.x * 128, h = blockIdx.y;
    const f32x4 fz = {0.0f, 0.0f, 0.0f, 0.0f};
    f32x4 acc[4] = {fz, fz, fz, fz};
    #pragma unroll
    for (int it = 0; it < 4; ++it) {
        int kk = it * 32;
        bf16x8 bfr = *(const bf16x8*)(vb + ((size_t)(h * 16 + ln)) * F_N + kk + quad * 8);
        #pragma unroll
        for (int mt = 0; mt < 4; ++mt) {
            bf16x8 af = *(const bf16x8*)(ub + ((size_t)h * MPAD + s0 + w * 64 + mt * 16 + ln) * F_N + kk + quad * 8);
            acc[mt] = __builtin_amdgcn_mfma_f32_16x16x32_bf16(af, bfr, acc[mt], 0, 0, 0);
        }
    }
    #pragma unroll
    for (int mt = 0; mt < 4; ++mt)
        #pragma unroll
        for (int r = 0; r < 4; ++r) {
            int s = s0 + w * 64 + mt * 16 + quad * 4 + r;
            G[(size_t)s * 64 + h * 16 + ln] = eluf(acc[mt][r]);
        }
}

// ---------------- K8: hmat = G@outW, att*h, elu,elu, log_softmax ----------------
__global__ __launch_bounds__(256) void k_fin(const float* __restrict__ G, const float* __restrict__ outW,
        const int* __restrict__ inter, float* __restrict__ out) {
    const int t = threadIdx.x;
    const int s0 = blockIdx.x * 16;
    __shared__ float Wl[64 * 16];
    __shared__ float Gl[16 * 64];
    #pragma unroll
    for (int k = 0; k < 4; ++k) {
        int i = k * 256 + t;
        Wl[i] = outW[i];
        Gl[i] = G[(size_t)(s0 + (i >> 6)) * 64 + (i & 63)];
    }
    __syncthreads();
    const int ss = t >> 4, c = t & 15, s = s0 + ss;
    float hm = 0.0f;
    #pragma unroll
    for (int j = 0; j < 64; ++j) hm += Gl[ss * 64 + j] * Wl[j * 16 + c];
    int msk = inter[s * 16 + c] > 0;
    int cn = msk;
    #pragma unroll
    for (int m = 8; m > 0; m >>= 1) cn += __shfl_xor(cn, m, 16);
    float attf = cn > 0 ? (msk ? 1.0f / (float)cn : 0.0f) : 0.0625f;
    float y = eluf(eluf(attf * hm));
    float mx = y;
    #pragma unroll
    for (int m = 8; m > 0; m >>= 1) mx = fmaxf(mx, __shfl_xor(mx, m, 16));
    float ex = expf(y - mx);
    float sm = ex;
    #pragma unroll
    for (int m = 8; m > 0; m >>= 1) sm += __shfl_xor(sm, m, 16);
    out[s * 16 + c] = y - mx - logf(sm);
}

extern "C" void kernel_launch(void* const* d_in, const int* in_sizes, int n_in,
                              void* d_out, int out_size, void* d_ws, size_t ws_size,
                              hipStream_t stream) {
    const int* inter = (const int*)d_in[0];
    const int* city  = (const int*)d_in[1];
    const int* prov  = (const int*)d_in[2];
    const int* src   = (const int*)d_in[3];
    const float* Sfeat = (const float*)d_in[4];
    const float* Rfeat = (const float*)d_in[5];
    const float* W1 = (const float*)d_in[6];
    const float* W2 = (const float*)d_in[7];
    const float* a  = (const float*)d_in[8];
    const float* g1 = (const float*)d_in[11];
    const float* b1 = (const float*)d_in[12];
    const float* g2 = (const float*)d_in[13];
    const float* b2 = (const float*)d_in[14];
    const float* outW = (const float*)d_in[15];
    float* out = (float*)d_out;

    char* p = (char*)d_ws;
    // ---- zeroed region (one memset) ----
    float* T    = (float*)p; p += (size_t)MPAD * F_N * 4;     // 5,177,344
    float* M    = (float*)p; p += 4 * 16 * F_N * 4;           // 32,768
    float* usum = (float*)p; p += 2048;
    float* usq  = (float*)p; p += 2048;
    u32*   cc   = (u32*)p;   p += 8192;
    u32*   pc   = (u32*)p;   p += 8192;
    size_t zbytes = (size_t)(p - (char*)d_ws);
    // ---- rest ----
    u64* tcity = (u64*)p; p += 32 * (size_t)MPAD * 8;
    u64* tprov = (u64*)p; p += 32 * (size_t)MPAD * 8;
    __bf16* YT  = (__bf16*)p; p += (size_t)F_N * B_N * 2;
    __bf16* ZT  = (__bf16*)p; p += (size_t)F_N * B_N * 2;
    __bf16* SfB = (__bf16*)p; p += (size_t)MPAD * F_N * 2;
    __bf16* W2T = (__bf16*)p; p += 512 * 128 * 2;
    __bf16* h1T = (__bf16*)p; p += 4 * 128 * 32 * 2;
    float*  q   = (float*)p;  p += 512;
    __bf16* Tb  = (__bf16*)p; p += (size_t)MPAD * F_N * 2;
    float*  h2  = (float*)p;  p += 4 * (size_t)MPAD * F_N * 4;
    float*  att = (float*)p;  p += 4 * (size_t)MPAD * 16 * 4;
    __bf16* attb= (__bf16*)p; p += 4 * (size_t)MPAD * 16 * 2;
    float*  P   = (float*)p;  p += 4 * (size_t)MPAD * F_N * 4;
    float* scale_u = (float*)p; p += 2048;
    float* shift_u = (float*)p; p += 2048;
    __bf16* vb  = (__bf16*)p; p += 4 * 16 * 128 * 2;
    __bf16* ub  = (__bf16*)p; p += 4 * (size_t)MPAD * F_N * 2;
    float*  G   = (float*)p;  p += (size_t)MPAD * 64 * 4;

    hipMemsetAsync(d_ws, 0, zbytes, stream);
    k_bits <<<dim3(20, 32, 2), 256, 0, stream>>>(city, prov, src, tcity, tprov, cc, pc);
    k_yz   <<<1024, 256, 0, stream>>>(Sfeat, src, cc, pc, YT, ZT);
    k_sfb  <<<5056, 256, 0, stream>>>(Sfeat, SfB);
    k_small<<<576, 128, 0, stream>>>(Rfeat, W1, W2, a, W2T, h1T, q);
    g_T    <<<dim3(79, 8), 256, 0, stream>>>(YT, ZT, tcity, tprov, T);
    k_tconv<<<5056, 256, 0, stream>>>(T, Tb);
    g_h2   <<<dim3(79, 4), 256, 0, stream>>>(SfB, W2T, h2);
    k_att  <<<MPAD, 64, 0, stream>>>(h2, a, q, inter, att, attb);
    g_P    <<<dim3(79, 4), 256, 0, stream>>>(Tb, W2T, attb, h1T, P, usum, usq);
    k_M    <<<dim3(50, 4), 128, 0, stream>>>(att, h2, M);
    k_bn   <<<4, 128, 0, stream>>>(usum, usq, M, g1, b1, g2, b2, scale_u, shift_u, vb);
    k_u    <<<20224, 256, 0, stream>>>(P, scale_u, shift_u, ub);
    g_G    <<<dim3(79, 4), 128, 0, stream>>>(ub, vb, G);
    k_fin  <<<625, 256, 0, stream>>>(G, outW, inter, out);
}

// Round 2
// 861.941 us; speedup vs baseline: 1.1358x; 1.1358x over previous
//
#include <hip/hip_runtime.h>
#include <hip/hip_bf16.h>
#include <stdint.h>

#define S_N 10000
#define MPAD 10112
#define B_N 2048
#define F_N 128

typedef __bf16 bf16x8 __attribute__((ext_vector_type(8)));
typedef __bf16 bf16x4 __attribute__((ext_vector_type(4)));
typedef float  f32x4  __attribute__((ext_vector_type(4)));
typedef unsigned long long u64;
typedef unsigned int u32;
typedef unsigned short u16;

union Bf8 { u16 us[8]; bf16x8 v; };
union Bh8 { __bf16 h[8]; bf16x8 v; };

__device__ __forceinline__ float lrelu02(float x) { return x >= 0.0f ? x : 0.2f * x; }
__device__ __forceinline__ float eluf(float x)    { return x > 0.0f ? x : expm1f(x); }

// ---------------- K1: adjacency gather -> popcounts + bit-transposed masks ----------------
__global__ __launch_bounds__(256) void k_bits(const int* __restrict__ adj_c,
        const int* __restrict__ adj_p, const int* __restrict__ src,
        u64* __restrict__ tcity, u64* __restrict__ tprov,
        u32* __restrict__ cc, u32* __restrict__ pc) {
    const int sc = blockIdx.x, wb = blockIdx.y, mat = blockIdx.z;
    const int t = threadIdx.x, l = t & 63, w = t >> 6;
    const int* adj = mat ? adj_p : adj_c;
    u64* tb = mat ? tprov : tcity;
    u32* cnt = mat ? pc : cc;
    __shared__ u64 wt[64][8];
    __shared__ u32 lc[64];
    if (t < 64) lc[t] = 0;
    __syncthreads();
    const int s1 = sc * 512 + t;
    const int s2 = s1 + 256;
    for (int bb = 0; bb < 64; ++bb) {
        int row = src[wb * 64 + bb];
        const int* rp = adj + (size_t)row * S_N;
        int v1 = (s1 < S_N) ? rp[s1] : 0;
        int v2 = (s2 < S_N) ? rp[s2] : 0;
        u64 b1 = __ballot(v1 > 0);
        u64 b2 = __ballot(v2 > 0);
        if (l == 0) {
            wt[bb][w] = b1;
            wt[bb][w + 4] = b2;
            atomicAdd(&lc[bb], (u32)(__popcll(b1) + __popcll(b2)));
        }
    }
    __syncthreads();
    if (t < 64) atomicAdd(&cnt[wb * 64 + t], lc[t]);
    for (int tile = w; tile < 8; tile += 4) {
        u64 wv = wt[l][tile];
        u64 myw = 0;
        #pragma unroll
        for (int j = 0; j < 64; ++j) {
            u64 bal = __ballot((int)((wv >> j) & 1ull));
            if (l == j) myw = bal;
        }
        int s = sc * 512 + tile * 64 + l;
        if (s < MPAD) tb[(size_t)wb * MPAD + s] = myw;
    }
}

// ---------------- K2: fused prep: Y^T/Z^T bf16 + Sfeat bf16 ----------------
__global__ __launch_bounds__(256) void k_prep(const float* __restrict__ Sfeat,
        const int* __restrict__ src, const u32* __restrict__ cc, const u32* __restrict__ pc,
        __bf16* __restrict__ YT, __bf16* __restrict__ ZT, __bf16* __restrict__ SfB) {
    const int bid = blockIdx.x, t = threadIdx.x;
    if (bid < 1024) {
        int idx = bid * 256 + t; // 128*2048
        int f = idx >> 11, b = idx & 2047;
        float sv = Sfeat[src[b] * F_N + f];
        float icc = cc[b] ? 1.0f / (float)cc[b] : 0.0f;
        float ipc = pc[b] ? 1.0f / (float)pc[b] : 0.0f;
        YT[f * B_N + b] = (__bf16)(sv * icc);
        ZT[f * B_N + b] = (__bf16)(sv * ipc);
    } else {
        int i = (bid - 1024) * 256 + t; // MPAD*128
        int s = i >> 7;
        SfB[i] = (__bf16)(s < S_N ? Sfeat[i] : 0.0f);
    }
}

// ---------------- K2c: W2T bf16, h1T bf16 (K padded to 32), q ----------------
__global__ __launch_bounds__(128) void k_small(const float* __restrict__ Rfeat,
        const float* __restrict__ W1, const float* __restrict__ W2, const float* __restrict__ a,
        __bf16* __restrict__ W2T, __bf16* __restrict__ h1T, float* __restrict__ q) {
    __shared__ float red[128];
    int bid = blockIdx.x, t = threadIdx.x;
    if (bid < 64) {
        int h = bid >> 4, r = bid & 15;
        float hv = 0.0f;
        const float* rf = Rfeat + r * F_N;
        const float* wp = W1 + h * F_N * F_N + t;
        for (int k = 0; k < F_N; ++k) hv += rf[k] * wp[k * F_N];
        h1T[(h * F_N + t) * 32 + r] = (__bf16)hv;
        h1T[(h * F_N + t) * 32 + 16 + r] = (__bf16)0.0f;
        red[t] = hv * a[h * 256 + t];
        __syncthreads();
        for (int off = 64; off > 0; off >>= 1) {
            if (t < off) red[t] += red[t + off];
            __syncthreads();
        }
        if (t == 0) q[h * 16 + r] = red[0];
    } else {
        int idx = (bid - 64) * 128 + t;
        int hn = idx >> 7, k = idx & 127;
        int h = hn >> 7, n = hn & 127;
        W2T[idx] = (__bf16)W2[(h * F_N + k) * F_N + n];
    }
}

// ---------------- G1: T partials (split-K=4, no atomics) ----------------
__global__ __launch_bounds__(256) void g_T(const __bf16* __restrict__ YT, const __bf16* __restrict__ ZT,
        const u64* __restrict__ tcity, const u64* __restrict__ tprov, float* __restrict__ Tp) {
    const int t = threadIdx.x, l = t & 63, w = t >> 6;
    const int wm = w >> 1, wn = w & 1;
    const int quad = l >> 4, ln = l & 15;
    const int s_blk = blockIdx.x * 128;
    const unsigned char* cb = (const unsigned char*)tcity;
    const unsigned char* pb = (const unsigned char*)tprov;
    const f32x4 fz = {0.0f, 0.0f, 0.0f, 0.0f};
    f32x4 acc[4][4];
    #pragma unroll
    for (int mt = 0; mt < 4; ++mt)
        #pragma unroll
        for (int nt = 0; nt < 4; ++nt) acc[mt][nt] = fz;
    const int k_base = blockIdx.y * 512;
    for (int it = 0; it < 16; ++it) {
        int kk = k_base + it * 32;
        bf16x8 Ya[4], Za[4];
        #pragma unroll
        for (int mt = 0; mt < 4; ++mt) {
            int f = wm * 64 + mt * 16 + ln;
            Ya[mt] = *(const bf16x8*)(YT + f * B_N + kk + quad * 8);
            Za[mt] = *(const bf16x8*)(ZT + f * B_N + kk + quad * 8);
        }
        bf16x8 Bc[4], Bp[4];
        #pragma unroll
        for (int nt = 0; nt < 4; ++nt) {
            int s = s_blk + wn * 64 + nt * 16 + ln;
            size_t base = ((size_t)(kk >> 6) * MPAD + s) * 8 + ((kk >> 3) & 7) + quad;
            unsigned int cby = cb[base], pby = pb[base];
            Bf8 uc, up;
            #pragma unroll
            for (int j = 0; j < 8; ++j) {
                uc.us[j] = ((cby >> j) & 1u) ? (u16)0x3F80 : (u16)0;
                up.us[j] = ((pby >> j) & 1u) ? (u16)0x3F80 : (u16)0;
            }
            Bc[nt] = uc.v; Bp[nt] = up.v;
        }
        #pragma unroll
        for (int mt = 0; mt < 4; ++mt)
            #pragma unroll
            for (int nt = 0; nt < 4; ++nt) {
                acc[mt][nt] = __builtin_amdgcn_mfma_f32_16x16x32_bf16(Ya[mt], Bc[nt], acc[mt][nt], 0, 0, 0);
                acc[mt][nt] = __builtin_amdgcn_mfma_f32_16x16x32_bf16(Za[mt], Bp[nt], acc[mt][nt], 0, 0, 0);
            }
    }
    float* tp = Tp + (size_t)blockIdx.y * ((size_t)MPAD * F_N);
    #pragma unroll
    for (int nt = 0; nt < 4; ++nt) {
        int s = s_blk + wn * 64 + nt * 16 + ln;
        #pragma unroll
        for (int mt = 0; mt < 4; ++mt) {
            int f0 = wm * 64 + mt * 16 + quad * 4;
            *(f32x4*)(tp + (size_t)s * F_N + f0) = acc[mt][nt];
        }
    }
}

// ---------------- K4: reduce 4 T partials -> Tb bf16 ----------------
__global__ __launch_bounds__(256) void k_tred(const float* __restrict__ Tp, __bf16* __restrict__ Tb) {
    int i4 = blockIdx.x * 256 + threadIdx.x; // MPAD*128/4 = 323584
    size_t base = (size_t)i4 * 4;
    const size_t stride = (size_t)MPAD * F_N;
    f32x4 s0 = *(const f32x4*)(Tp + base);
    f32x4 s1 = *(const f32x4*)(Tp + stride + base);
    f32x4 s2 = *(const f32x4*)(Tp + 2 * stride + base);
    f32x4 s3 = *(const f32x4*)(Tp + 3 * stride + base);
    f32x4 sum = s0 + s1 + s2 + s3;
    bf16x4 o;
    #pragma unroll
    for (int j = 0; j < 4; ++j) o[j] = (__bf16)sum[j];
    *(bf16x4*)(Tb + base) = o;
}

// ---------------- G2: h2[h] = Sfeat@W2[h] + fused attention softmax ----------------
__global__ __launch_bounds__(256) void g_h2att(const __bf16* __restrict__ A, const __bf16* __restrict__ W2T,
        const float* __restrict__ a, const float* __restrict__ q, const int* __restrict__ inter,
        __bf16* __restrict__ h2b, float* __restrict__ att, __bf16* __restrict__ attb) {
    const int t = threadIdx.x, l = t & 63, w = t >> 6;
    const int wm = w >> 1, wn = w & 1, quad = l >> 4, ln = l & 15;
    const int s0 = blockIdx.x * 128, h = blockIdx.y;
    const f32x4 fz = {0.0f, 0.0f, 0.0f, 0.0f};
    f32x4 acc[4][4];
    #pragma unroll
    for (int mt = 0; mt < 4; ++mt)
        #pragma unroll
        for (int nt = 0; nt < 4; ++nt) acc[mt][nt] = fz;
    #pragma unroll
    for (int it = 0; it < 4; ++it) {
        int kk = it * 32;
        bf16x8 af[4], bfr[4];
        #pragma unroll
        for (int mt = 0; mt < 4; ++mt)
            af[mt] = *(const bf16x8*)(A + (size_t)(s0 + wm * 64 + mt * 16 + ln) * F_N + kk + quad * 8);
        #pragma unroll
        for (int nt = 0; nt < 4; ++nt)
            bfr[nt] = *(const bf16x8*)(W2T + (size_t)(h * F_N + wn * 64 + nt * 16 + ln) * F_N + kk + quad * 8);
        #pragma unroll
        for (int mt = 0; mt < 4; ++mt)
            #pragma unroll
            for (int nt = 0; nt < 4; ++nt)
                acc[mt][nt] = __builtin_amdgcn_mfma_f32_16x16x32_bf16(af[mt], bfr[nt], acc[mt][nt], 0, 0, 0);
    }
    // write h2 bf16 (for k_M) + score partials p[s] = sum_f h2[s][f]*a[F:][f]
    __shared__ float ps[128];
    if (t < 128) ps[t] = 0.0f;
    __syncthreads();
    float a2v[4];
    #pragma unroll
    for (int nt = 0; nt < 4; ++nt) a2v[nt] = a[h * 256 + 128 + wn * 64 + nt * 16 + ln];
    #pragma unroll
    for (int mt = 0; mt < 4; ++mt) {
        #pragma unroll
        for (int r = 0; r < 4; ++r) {
            int s = s0 + wm * 64 + mt * 16 + quad * 4 + r;
            float pp = 0.0f;
            #pragma unroll
            for (int nt = 0; nt < 4; ++nt) {
                float val = acc[mt][nt][r];
                h2b[((size_t)h * MPAD + s) * F_N + wn * 64 + nt * 16 + ln] = (__bf16)val;
                pp += val * a2v[nt];
            }
            #pragma unroll
            for (int m = 8; m > 0; m >>= 1) pp += __shfl_xor(pp, m, 16);
            if (ln == 0) atomicAdd(&ps[wm * 64 + mt * 16 + quad * 4 + r], pp);
        }
    }
    __syncthreads();
    if (t < 128) {
        int s = s0 + t;
        if (s < S_N) {
            float pv = ps[t];
            float e[16];
            int msk[16], cn = 0;
            float mx = -3e38f;
            #pragma unroll
            for (int c = 0; c < 16; ++c) {
                msk[c] = inter[s * 16 + c] > 0;
                cn += msk[c];
                e[c] = lrelu02(pv + q[h * 16 + c]);
                if (msk[c]) mx = fmaxf(mx, e[c]);
            }
            float sm = 0.0f;
            #pragma unroll
            for (int c = 0; c < 16; ++c) {
                e[c] = msk[c] ? expf(e[c] - mx) : 0.0f;
                sm += e[c];
            }
            float inv = cn > 0 ? 1.0f / sm : 0.0f;
            #pragma unroll
            for (int c = 0; c < 16; ++c) {
                float av = cn > 0 ? e[c] * inv : 0.0625f;
                att[((size_t)h * MPAD + s) * 16 + c] = av;
                attb[((size_t)h * MPAD + s) * 16 + c] = (__bf16)av;
            }
        } else {
            #pragma unroll
            for (int c = 0; c < 16; ++c) {
                att[((size_t)h * MPAD + s) * 16 + c] = 0.0f;
                attb[((size_t)h * MPAD + s) * 16 + c] = (__bf16)0.0f;
            }
        }
    }
}

// ---------------- G3: P[h] = T@W2[h] + att[h]@h1[h], + BN column sums ----------------
__global__ __launch_bounds__(256) void g_P(const __bf16* __restrict__ Tb, const __bf16* __restrict__ W2T,
        const __bf16* __restrict__ attb, const __bf16* __restrict__ h1T,
        float* __restrict__ P, float* __restrict__ usum, float* __restrict__ usq) {
    const int t = threadIdx.x, l = t & 63, w = t >> 6;
    const int wm = w >> 1, wn = w & 1, quad = l >> 4, ln = l & 15;
    const int s0 = blockIdx.x * 128, h = blockIdx.y;
    const f32x4 fz = {0.0f, 0.0f, 0.0f, 0.0f};
    f32x4 acc[4][4];
    #pragma unroll
    for (int mt = 0; mt < 4; ++mt)
        #pragma unroll
        for (int nt = 0; nt < 4; ++nt) acc[mt][nt] = fz;
    {
        bf16x8 a2[4], b2[4];
        #pragma unroll
        for (int mt = 0; mt < 4; ++mt) {
            int s = s0 + wm * 64 + mt * 16 + ln;
            Bf8 az;
            az.v = *(const bf16x8*)(attb + ((size_t)h * MPAD + s) * 16 + (quad & 1) * 8);
            if (quad >= 2) {
                #pragma unroll
                for (int j = 0; j < 8; ++j) az.us[j] = 0;
            }
            a2[mt] = az.v;
        }
        #pragma unroll
        for (int nt = 0; nt < 4; ++nt) {
            int f = wn * 64 + nt * 16 + ln;
            b2[nt] = *(const bf16x8*)(h1T + ((size_t)(h * F_N + f)) * 32 + quad * 8);
        }
        #pragma unroll
        for (int mt = 0; mt < 4; ++mt)
            #pragma unroll
            for (int nt = 0; nt < 4; ++nt)
                acc[mt][nt] = __builtin_amdgcn_mfma_f32_16x16x32_bf16(a2[mt], b2[nt], acc[mt][nt], 0, 0, 0);
    }
    #pragma unroll
    for (int it = 0; it < 4; ++it) {
        int kk = it * 32;
        bf16x8 af[4], bfr[4];
        #pragma unroll
        for (int mt = 0; mt < 4; ++mt)
            af[mt] = *(const bf16x8*)(Tb + (size_t)(s0 + wm * 64 + mt * 16 + ln) * F_N + kk + quad * 8);
        #pragma unroll
        for (int nt = 0; nt < 4; ++nt)
            bfr[nt] = *(const bf16x8*)(W2T + (size_t)(h * F_N + wn * 64 + nt * 16 + ln) * F_N + kk + quad * 8);
        #pragma unroll
        for (int mt = 0; mt < 4; ++mt)
            #pragma unroll
            for (int nt = 0; nt < 4; ++nt)
                acc[mt][nt] = __builtin_amdgcn_mfma_f32_16x16x32_bf16(af[mt], bfr[nt], acc[mt][nt], 0, 0, 0);
    }
    __shared__ float lsum[128], lsq[128];
    if (t < 128) { lsum[t] = 0.0f; lsq[t] = 0.0f; }
    __syncthreads();
    #pragma unroll
    for (int nt = 0; nt < 4; ++nt) {
        int f = wn * 64 + nt * 16 + ln;
        float p1 = 0.0f, p2 = 0.0f;
        #pragma unroll
        for (int mt = 0; mt < 4; ++mt) {
            int sb = s0 + wm * 64 + mt * 16 + quad * 4;
            #pragma unroll
            for (int r = 0; r < 4; ++r) {
                float val = acc[mt][nt][r];
                P[((size_t)h * MPAD + sb + r) * F_N + f] = val;
                p1 += val; p2 += val * val;
            }
        }
        atomicAdd(&lsum[f], p1);
        atomicAdd(&lsq[f], p2);
    }
    __syncthreads();
    if (t < 128) {
        atomicAdd(&usum[h * F_N + t], lsum[t]);
        atomicAdd(&usq[h * F_N + t], lsq[t]);
    }
}

// ---------------- K6: M[h] = att[h]^T @ h2[h] ----------------
__global__ __launch_bounds__(128) void k_M(const float* __restrict__ att, const __bf16* __restrict__ h2b,
        float* __restrict__ M) {
    const int h = blockIdx.y, t = threadIdx.x;
    const int s0 = blockIdx.x * 200;
    float acc[16] = {};
    for (int s = s0; s < s0 + 200; ++s) {
        float hv = (float)h2b[((size_t)h * MPAD + s) * F_N + t];
        const float* ar = att + ((size_t)h * MPAD + s) * 16;
        #pragma unroll
        for (int r = 0; r < 16; ++r) acc[r] += ar[r] * hv;
    }
    #pragma unroll
    for (int r = 0; r < 16; ++r) atomicAdd(&M[(h * 16 + r) * F_N + t], acc[r]);
}

// ---------------- K7: BN finalize + v = lrelu(bn1(M)) ----------------
__global__ __launch_bounds__(128) void k_bn(const float* __restrict__ usum, const float* __restrict__ usq,
        const float* __restrict__ M, const float* __restrict__ g1, const float* __restrict__ b1,
        const float* __restrict__ g2, const float* __restrict__ b2,
        float* __restrict__ scale_u, float* __restrict__ shift_u, __bf16* __restrict__ vb) {
    const int h = blockIdx.x, f = threadIdx.x;
    const int i = h * F_N + f;
    float mean = usum[i] * (1.0f / S_N);
    float var = usq[i] * (1.0f / S_N) - mean * mean;
    float sc = g2[i] * rsqrtf(var + 1e-5f);
    scale_u[i] = sc;
    shift_u[i] = b2[i] - mean * sc;
    float mv[16], s1 = 0.0f, s2 = 0.0f;
    #pragma unroll
    for (int r = 0; r < 16; ++r) {
        mv[r] = M[(h * 16 + r) * F_N + f];
        s1 += mv[r]; s2 += mv[r] * mv[r];
    }
    float m1 = s1 * 0.0625f, v1 = s2 * 0.0625f - m1 * m1;
    float g = g1[i] * rsqrtf(v1 + 1e-5f);
    float bb = b1[i] - m1 * g;
    #pragma unroll
    for (int r = 0; r < 16; ++r)
        vb[(h * 16 + r) * F_N + f] = (__bf16)lrelu02(mv[r] * g + bb);
}

// ---------------- G4: G = elu(lrelu(bn2(P)) @ v^T), BN applied on the fly ----------------
__global__ __launch_bounds__(128) void g_G(const float* __restrict__ P, const float* __restrict__ scale_u,
        const float* __restrict__ shift_u, const __bf16* __restrict__ vb, float* __restrict__ G) {
    const int t = threadIdx.x, l = t & 63, w = t >> 6;
    const int quad = l >> 4, ln = l & 15;
    const int s0 = blockIdx.x * 128, h = blockIdx.y;
    __shared__ float scl[128], shl[128];
    scl[t] = scale_u[h * F_N + t];
    shl[t] = shift_u[h * F_N + t];
    __syncthreads();
    const f32x4 fz = {0.0f, 0.0f, 0.0f, 0.0f};
    f32x4 acc[4] = {fz, fz, fz, fz};
    #pragma unroll
    for (int it = 0; it < 4; ++it) {
        int kk = it * 32;
        bf16x8 bfr = *(const bf16x8*)(vb + ((size_t)(h * 16 + ln)) * F_N + kk + quad * 8);
        #pragma unroll
        for (int mt = 0; mt < 4; ++mt) {
            int s = s0 + w * 64 + mt * 16 + ln;
            const float* pp = P + ((size_t)h * MPAD + s) * F_N + kk + quad * 8;
            f32x4 p0 = *(const f32x4*)pp;
            f32x4 p1 = *(const f32x4*)(pp + 4);
            Bh8 af;
            #pragma unroll
            for (int j = 0; j < 4; ++j) {
                int f = kk + quad * 8 + j;
                af.h[j]     = (__bf16)lrelu02(p0[j] * scl[f]     + shl[f]);
                af.h[j + 4] = (__bf16)lrelu02(p1[j] * scl[f + 4] + shl[f + 4]);
            }
            acc[mt] = __builtin_amdgcn_mfma_f32_16x16x32_bf16(af.v, bfr, acc[mt], 0, 0, 0);
        }
    }
    #pragma unroll
    for (int mt = 0; mt < 4; ++mt)
        #pragma unroll
        for (int r = 0; r < 4; ++r) {
            int s = s0 + w * 64 + mt * 16 + quad * 4 + r;
            G[(size_t)s * 64 + h * 16 + ln] = eluf(acc[mt][r]);
        }
}

// ---------------- K8: hmat = G@outW, att*h, elu,elu, log_softmax ----------------
__global__ __launch_bounds__(256) void k_fin(const float* __restrict__ G, const float* __restrict__ outW,
        const int* __restrict__ inter, float* __restrict__ out) {
    const int t = threadIdx.x;
    const int s0 = blockIdx.x * 16;
    __shared__ float Wl[64 * 16];
    __shared__ float Gl[16 * 64];
    #pragma unroll
    for (int k = 0; k < 4; ++k) {
        int i = k * 256 + t;
        Wl[i] = outW[i];
        Gl[i] = G[(size_t)(s0 + (i >> 6)) * 64 + (i & 63)];
    }
    __syncthreads();
    const int ss = t >> 4, c = t & 15, s = s0 + ss;
    float hm = 0.0f;
    #pragma unroll
    for (int j = 0; j < 64; ++j) hm += Gl[ss * 64 + j] * Wl[j * 16 + c];
    int msk = inter[s * 16 + c] > 0;
    int cn = msk;
    #pragma unroll
    for (int m = 8; m > 0; m >>= 1) cn += __shfl_xor(cn, m, 16);
    float attf = cn > 0 ? (msk ? 1.0f / (float)cn : 0.0f) : 0.0625f;
    float y = eluf(eluf(attf * hm));
    float mx = y;
    #pragma unroll
    for (int m = 8; m > 0; m >>= 1) mx = fmaxf(mx, __shfl_xor(mx, m, 16));
    float ex = expf(y - mx);
    float sm = ex;
    #pragma unroll
    for (int m = 8; m > 0; m >>= 1) sm += __shfl_xor(sm, m, 16);
    out[s * 16 + c] = y - mx - logf(sm);
}

extern "C" void kernel_launch(void* const* d_in, const int* in_sizes, int n_in,
                              void* d_out, int out_size, void* d_ws, size_t ws_size,
                              hipStream_t stream) {
    const int* inter = (const int*)d_in[0];
    const int* city  = (const int*)d_in[1];
    const int* prov  = (const int*)d_in[2];
    const int* src   = (const int*)d_in[3];
    const float* Sfeat = (const float*)d_in[4];
    const float* Rfeat = (const float*)d_in[5];
    const float* W1 = (const float*)d_in[6];
    const float* W2 = (const float*)d_in[7];
    const float* a  = (const float*)d_in[8];
    const float* g1 = (const float*)d_in[11];
    const float* b1 = (const float*)d_in[12];
    const float* g2 = (const float*)d_in[13];
    const float* b2 = (const float*)d_in[14];
    const float* outW = (const float*)d_in[15];
    float* out = (float*)d_out;

    char* p = (char*)d_ws;
    // ---- zeroed region ----
    float* M    = (float*)p; p += 4 * 16 * F_N * 4;   // 32768
    float* usum = (float*)p; p += 2048;
    float* usq  = (float*)p; p += 2048;
    u32*   cc   = (u32*)p;   p += 8192;
    u32*   pc   = (u32*)p;   p += 8192;
    size_t zbytes = (size_t)(p - (char*)d_ws);        // 53248
    // ---- rest ----
    u64* tcity = (u64*)p; p += 32 * (size_t)MPAD * 8;
    u64* tprov = (u64*)p; p += 32 * (size_t)MPAD * 8;
    __bf16* YT  = (__bf16*)p; p += (size_t)F_N * B_N * 2;
    __bf16* ZT  = (__bf16*)p; p += (size_t)F_N * B_N * 2;
    __bf16* SfB = (__bf16*)p; p += (size_t)MPAD * F_N * 2;
    __bf16* W2T = (__bf16*)p; p += 512 * 128 * 2;
    __bf16* h1T = (__bf16*)p; p += 4 * 128 * 32 * 2;
    float*  q   = (float*)p;  p += 512;
    float*  Tp  = (float*)p;  p += 4 * (size_t)MPAD * F_N * 4;   // split-K partials
    __bf16* Tb  = (__bf16*)p; p += (size_t)MPAD * F_N * 2;
    __bf16* h2b = (__bf16*)p; p += 4 * (size_t)MPAD * F_N * 2;
    float*  att = (float*)p;  p += 4 * (size_t)MPAD * 16 * 4;
    __bf16* attb= (__bf16*)p; p += 4 * (size_t)MPAD * 16 * 2;
    float*  P   = (float*)p;  p += 4 * (size_t)MPAD * F_N * 4;
    float* scale_u = (float*)p; p += 2048;
    float* shift_u = (float*)p; p += 2048;
    __bf16* vb  = (__bf16*)p; p += 4 * 16 * 128 * 2;
    float*  G   = (float*)p;  p += (size_t)MPAD * 64 * 4;

    hipMemsetAsync(d_ws, 0, zbytes, stream);
    k_bits <<<dim3(20, 32, 2), 256, 0, stream>>>(city, prov, src, tcity, tprov, cc, pc);
    k_prep <<<6080, 256, 0, stream>>>(Sfeat, src, cc, pc, YT, ZT, SfB);
    k_small<<<576, 128, 0, stream>>>(Rfeat, W1, W2, a, W2T, h1T, q);
    g_T    <<<dim3(79, 4), 256, 0, stream>>>(YT, ZT, tcity, tprov, Tp);
    k_tred <<<1264, 256, 0, stream>>>(Tp, Tb);
    g_h2att<<<dim3(79, 4), 256, 0, stream>>>(SfB, W2T, a, q, inter, h2b, att, attb);
    g_P    <<<dim3(79, 4), 256, 0, stream>>>(Tb, W2T, attb, h1T, P, usum, usq);
    k_M    <<<dim3(50, 4), 128, 0, stream>>>(att, h2b, M);
    k_bn   <<<4, 128, 0, stream>>>(usum, usq, M, g1, b1, g2, b2, scale_u, shift_u, vb);
    g_G    <<<dim3(79, 4), 128, 0, stream>>>(P, scale_u, shift_u, vb, G);
    k_fin  <<<625, 256, 0, stream>>>(G, outW, inter, out);
}

// Round 3
// 791.122 us; speedup vs baseline: 1.2375x; 1.0895x over previous
//
#include <hip/hip_runtime.h>
#include <hip/hip_bf16.h>
#include <stdint.h>

#define S_N 10000
#define MPAD 10112
#define B_N 2048
#define F_N 128

typedef __bf16 bf16x8 __attribute__((ext_vector_type(8)));
typedef __bf16 bf16x4 __attribute__((ext_vector_type(4)));
typedef float  f32x4  __attribute__((ext_vector_type(4)));
typedef unsigned long long u64;
typedef unsigned int u32;
typedef unsigned short u16;

union Bf8 { u16 us[8]; bf16x8 v; };
union Bh8 { __bf16 h[8]; bf16x8 v; };

__device__ __forceinline__ float lrelu02(float x) { return x >= 0.0f ? x : 0.2f * x; }
__device__ __forceinline__ float eluf(float x)    { return x > 0.0f ? x : expm1f(x); }

// ---------------- K1: k_bits + SfB conv + W2T/h1T/q prep (independent parts, one dispatch) ----
// blocks 0..1279: adjacency gather -> bit-transpose; 1280..6335: SfB; 6336..6591: W2T; 6592..6655: h1T/q
__global__ __launch_bounds__(256) void k_bits_pre(const int* __restrict__ adj_c,
        const int* __restrict__ adj_p, const int* __restrict__ src,
        const float* __restrict__ Sfeat, const float* __restrict__ Rfeat,
        const float* __restrict__ W1, const float* __restrict__ W2, const float* __restrict__ a,
        u64* __restrict__ tcity, u64* __restrict__ tprov,
        u32* __restrict__ cc, u32* __restrict__ pc,
        __bf16* __restrict__ SfB, __bf16* __restrict__ W2T, __bf16* __restrict__ h1T,
        float* __restrict__ q) {
    const int bid = blockIdx.x, t = threadIdx.x;
    if (bid < 1280) {
        const int sc = bid % 20, wb = (bid / 20) % 32, mat = bid / 640;
        const int l = t & 63, w = t >> 6;
        const int* adj = mat ? adj_p : adj_c;
        u64* tb = mat ? tprov : tcity;
        u32* cnt = mat ? pc : cc;
        __shared__ u64 wt[64][8];
        __shared__ u32 lc[64];
        if (t < 64) lc[t] = 0;
        __syncthreads();
        const int s1 = sc * 512 + t;
        const int s2 = s1 + 256;
        for (int bb = 0; bb < 64; ++bb) {
            int row = src[wb * 64 + bb];
            const int* rp = adj + (size_t)row * S_N;
            int v1 = (s1 < S_N) ? rp[s1] : 0;
            int v2 = (s2 < S_N) ? rp[s2] : 0;
            u64 b1 = __ballot(v1 > 0);
            u64 b2 = __ballot(v2 > 0);
            if (l == 0) {
                wt[bb][w] = b1;
                wt[bb][w + 4] = b2;
                atomicAdd(&lc[bb], (u32)(__popcll(b1) + __popcll(b2)));
            }
        }
        __syncthreads();
        if (t < 64) atomicAdd(&cnt[wb * 64 + t], lc[t]);
        for (int tile = w; tile < 8; tile += 4) {
            u64 wv = wt[l][tile];
            u64 myw = 0;
            #pragma unroll
            for (int j = 0; j < 64; ++j) {
                u64 bal = __ballot((int)((wv >> j) & 1ull));
                if (l == j) myw = bal;
            }
            int s = sc * 512 + tile * 64 + l;
            if (s < MPAD) tb[(size_t)wb * MPAD + s] = myw;
        }
    } else if (bid < 6336) {
        int i = (bid - 1280) * 256 + t; // MPAD*128
        int s = i >> 7;
        SfB[i] = (__bf16)(s < S_N ? Sfeat[i] : 0.0f);
    } else if (bid < 6592) {
        int idx = (bid - 6336) * 256 + t; // 65536
        int hn = idx >> 7, k = idx & 127;
        int h = hn >> 7, n = hn & 127;
        W2T[idx] = (__bf16)W2[(h * F_N + k) * F_N + n];
    } else {
        __shared__ float red[256];
        int b2i = bid - 6592;
        int h = b2i >> 4, r = b2i & 15;
        float hv = 0.0f;
        if (t < 128) {
            const float* rf = Rfeat + r * F_N;
            const float* wp = W1 + h * F_N * F_N + t;
            for (int k = 0; k < F_N; ++k) hv += rf[k] * wp[k * F_N];
        }
        red[t] = (t < 128) ? hv * a[h * 256 + t] : 0.0f;
        __syncthreads();
        for (int off = 128; off > 0; off >>= 1) {
            if (t < off) red[t] += red[t + off];
            __syncthreads();
        }
        if (t == 0) q[h * 16 + r] = red[0];
        if (t < 128) {
            h1T[(h * F_N + t) * 32 + r] = (__bf16)hv;
            h1T[(h * F_N + t) * 32 + 16 + r] = (__bf16)0.0f;
        }
    }
}

// ---------------- K2: Y^T/Z^T (needs counts from K1) ----------------
__global__ __launch_bounds__(256) void k_yz(const float* __restrict__ Sfeat,
        const int* __restrict__ src, const u32* __restrict__ cc, const u32* __restrict__ pc,
        __bf16* __restrict__ YT, __bf16* __restrict__ ZT) {
    int idx = blockIdx.x * 256 + threadIdx.x; // 128*2048
    int f = idx >> 11, b = idx & 2047;
    float sv = Sfeat[src[b] * F_N + f];
    float icc = cc[b] ? 1.0f / (float)cc[b] : 0.0f;
    float ipc = pc[b] ? 1.0f / (float)pc[b] : 0.0f;
    YT[f * B_N + b] = (__bf16)(sv * icc);
    ZT[f * B_N + b] = (__bf16)(sv * ipc);
}

// ---------------- G1: T partials (split-K=4, no atomics) ----------------
__global__ __launch_bounds__(256) void g_T(const __bf16* __restrict__ YT, const __bf16* __restrict__ ZT,
        const u64* __restrict__ tcity, const u64* __restrict__ tprov, float* __restrict__ Tp) {
    const int t = threadIdx.x, l = t & 63, w = t >> 6;
    const int wm = w >> 1, wn = w & 1;
    const int quad = l >> 4, ln = l & 15;
    const int s_blk = blockIdx.x * 128;
    const unsigned char* cb = (const unsigned char*)tcity;
    const unsigned char* pb = (const unsigned char*)tprov;
    const f32x4 fz = {0.0f, 0.0f, 0.0f, 0.0f};
    f32x4 acc[4][4];
    #pragma unroll
    for (int mt = 0; mt < 4; ++mt)
        #pragma unroll
        for (int nt = 0; nt < 4; ++nt) acc[mt][nt] = fz;
    const int k_base = blockIdx.y * 512;
    for (int it = 0; it < 16; ++it) {
        int kk = k_base + it * 32;
        bf16x8 Ya[4], Za[4];
        #pragma unroll
        for (int mt = 0; mt < 4; ++mt) {
            int f = wm * 64 + mt * 16 + ln;
            Ya[mt] = *(const bf16x8*)(YT + f * B_N + kk + quad * 8);
            Za[mt] = *(const bf16x8*)(ZT + f * B_N + kk + quad * 8);
        }
        bf16x8 Bc[4], Bp[4];
        #pragma unroll
        for (int nt = 0; nt < 4; ++nt) {
            int s = s_blk + wn * 64 + nt * 16 + ln;
            size_t base = ((size_t)(kk >> 6) * MPAD + s) * 8 + ((kk >> 3) & 7) + quad;
            unsigned int cby = cb[base], pby = pb[base];
            Bf8 uc, up;
            #pragma unroll
            for (int j = 0; j < 8; ++j) {
                uc.us[j] = ((cby >> j) & 1u) ? (u16)0x3F80 : (u16)0;
                up.us[j] = ((pby >> j) & 1u) ? (u16)0x3F80 : (u16)0;
            }
            Bc[nt] = uc.v; Bp[nt] = up.v;
        }
        #pragma unroll
        for (int mt = 0; mt < 4; ++mt)
            #pragma unroll
            for (int nt = 0; nt < 4; ++nt) {
                acc[mt][nt] = __builtin_amdgcn_mfma_f32_16x16x32_bf16(Ya[mt], Bc[nt], acc[mt][nt], 0, 0, 0);
                acc[mt][nt] = __builtin_amdgcn_mfma_f32_16x16x32_bf16(Za[mt], Bp[nt], acc[mt][nt], 0, 0, 0);
            }
    }
    float* tp = Tp + (size_t)blockIdx.y * ((size_t)MPAD * F_N);
    #pragma unroll
    for (int nt = 0; nt < 4; ++nt) {
        int s = s_blk + wn * 64 + nt * 16 + ln;
        #pragma unroll
        for (int mt = 0; mt < 4; ++mt) {
            int f0 = wm * 64 + mt * 16 + quad * 4;
            *(f32x4*)(tp + (size_t)s * F_N + f0) = acc[mt][nt];
        }
    }
}

// ---------------- K3: reduce 4 T partials -> Tb bf16 ----------------
__global__ __launch_bounds__(256) void k_tred(const float* __restrict__ Tp, __bf16* __restrict__ Tb) {
    int i4 = blockIdx.x * 256 + threadIdx.x;
    size_t base = (size_t)i4 * 4;
    const size_t stride = (size_t)MPAD * F_N;
    f32x4 s0 = *(const f32x4*)(Tp + base);
    f32x4 s1 = *(const f32x4*)(Tp + stride + base);
    f32x4 s2 = *(const f32x4*)(Tp + 2 * stride + base);
    f32x4 s3 = *(const f32x4*)(Tp + 3 * stride + base);
    f32x4 sum = s0 + s1 + s2 + s3;
    bf16x4 o;
    #pragma unroll
    for (int j = 0; j < 4; ++j) o[j] = (__bf16)sum[j];
    *(bf16x4*)(Tb + base) = o;
}

// ---------------- G2: h2 = Sfeat@W2 + attention softmax + fused M-partial MFMA ----------------
__global__ __launch_bounds__(256) void g_h2attM(const __bf16* __restrict__ A, const __bf16* __restrict__ W2T,
        const float* __restrict__ a, const float* __restrict__ q, const int* __restrict__ inter,
        __bf16* __restrict__ attb, float* __restrict__ Mg) {
    const int t = threadIdx.x, l = t & 63, w = t >> 6;
    const int wm = w >> 1, wn = w & 1, quad = l >> 4, ln = l & 15;
    const int s0 = blockIdx.x * 128, h = blockIdx.y;
    __shared__ __bf16 h2T[128 * 136];   // [f][s_local], stride 136
    __shared__ __bf16 attT[16 * 136];   // [c][s_local]
    __shared__ float ps[128];
    if (t < 128) ps[t] = 0.0f;
    __syncthreads();
    const f32x4 fz = {0.0f, 0.0f, 0.0f, 0.0f};
    f32x4 acc[4][4];
    #pragma unroll
    for (int mt = 0; mt < 4; ++mt)
        #pragma unroll
        for (int nt = 0; nt < 4; ++nt) acc[mt][nt] = fz;
    #pragma unroll
    for (int it = 0; it < 4; ++it) {
        int kk = it * 32;
        bf16x8 af[4], bfr[4];
        #pragma unroll
        for (int mt = 0; mt < 4; ++mt)
            af[mt] = *(const bf16x8*)(A + (size_t)(s0 + wm * 64 + mt * 16 + ln) * F_N + kk + quad * 8);
        #pragma unroll
        for (int nt = 0; nt < 4; ++nt)
            bfr[nt] = *(const bf16x8*)(W2T + (size_t)(h * F_N + wn * 64 + nt * 16 + ln) * F_N + kk + quad * 8);
        #pragma unroll
        for (int mt = 0; mt < 4; ++mt)
            #pragma unroll
            for (int nt = 0; nt < 4; ++nt)
                acc[mt][nt] = __builtin_amdgcn_mfma_f32_16x16x32_bf16(af[mt], bfr[nt], acc[mt][nt], 0, 0, 0);
    }
    // write h2 tile (transposed, bf16) to LDS + score partials
    float a2v[4];
    #pragma unroll
    for (int nt = 0; nt < 4; ++nt) a2v[nt] = a[h * 256 + 128 + wn * 64 + nt * 16 + ln];
    #pragma unroll
    for (int mt = 0; mt < 4; ++mt) {
        #pragma unroll
        for (int nt = 0; nt < 4; ++nt) {
            bf16x4 o;
            #pragma unroll
            for (int j = 0; j < 4; ++j) o[j] = (__bf16)acc[mt][nt][j];
            *(bf16x4*)(&h2T[(wn * 64 + nt * 16 + ln) * 136 + wm * 64 + mt * 16 + quad * 4]) = o;
        }
        #pragma unroll
        for (int r = 0; r < 4; ++r) {
            float pp = 0.0f;
            #pragma unroll
            for (int nt = 0; nt < 4; ++nt) pp += acc[mt][nt][r] * a2v[nt];
            #pragma unroll
            for (int m = 8; m > 0; m >>= 1) pp += __shfl_xor(pp, m, 16);
            if (ln == 0) atomicAdd(&ps[wm * 64 + mt * 16 + quad * 4 + r], pp);
        }
    }
    __syncthreads();
    // softmax per row
    if (t < 128) {
        int s = s0 + t;
        if (s < S_N) {
            float pv = ps[t];
            float e[16];
            int msk[16], cn = 0;
            float mx = -3e38f;
            #pragma unroll
            for (int c = 0; c < 16; ++c) {
                msk[c] = inter[s * 16 + c] > 0;
                cn += msk[c];
                e[c] = lrelu02(pv + q[h * 16 + c]);
                if (msk[c]) mx = fmaxf(mx, e[c]);
            }
            float sm = 0.0f;
            #pragma unroll
            for (int c = 0; c < 16; ++c) {
                e[c] = msk[c] ? expf(e[c] - mx) : 0.0f;
                sm += e[c];
            }
            float inv = cn > 0 ? 1.0f / sm : 0.0f;
            #pragma unroll
            for (int c = 0; c < 16; ++c) {
                float av = cn > 0 ? e[c] * inv : 0.0625f;
                attb[((size_t)h * MPAD + s) * 16 + c] = (__bf16)av;
                attT[c * 136 + t] = (__bf16)av;
            }
        } else {
            #pragma unroll
            for (int c = 0; c < 16; ++c) {
                attb[((size_t)h * MPAD + s) * 16 + c] = (__bf16)0.0f;
                attT[c * 136 + t] = (__bf16)0.0f;
            }
        }
    }
    __syncthreads();
    // M partial = att^T @ h2 over this block's 128 rows; wave w does f-tiles {2w, 2w+1}
    #pragma unroll
    for (int fi = 0; fi < 2; ++fi) {
        int ft = 2 * w + fi;
        f32x4 macc = fz;
        #pragma unroll
        for (int kit = 0; kit < 4; ++kit) {
            bf16x8 av = *(const bf16x8*)(&attT[ln * 136 + kit * 32 + quad * 8]);
            bf16x8 bv = *(const bf16x8*)(&h2T[(ft * 16 + ln) * 136 + kit * 32 + quad * 8]);
            macc = __builtin_amdgcn_mfma_f32_16x16x32_bf16(av, bv, macc, 0, 0, 0);
        }
        #pragma unroll
        for (int r = 0; r < 4; ++r)
            atomicAdd(&Mg[(h * 16 + quad * 4 + r) * F_N + ft * 16 + ln], macc[r]);
    }
}

// ---------------- G3: P = T@W2 + att@h1, + BN column sums ----------------
__global__ __launch_bounds__(256) void g_P(const __bf16* __restrict__ Tb, const __bf16* __restrict__ W2T,
        const __bf16* __restrict__ attb, const __bf16* __restrict__ h1T,
        float* __restrict__ P, float* __restrict__ usum, float* __restrict__ usq) {
    const int t = threadIdx.x, l = t & 63, w = t >> 6;
    const int wm = w >> 1, wn = w & 1, quad = l >> 4, ln = l & 15;
    const int s0 = blockIdx.x * 128, h = blockIdx.y;
    const f32x4 fz = {0.0f, 0.0f, 0.0f, 0.0f};
    f32x4 acc[4][4];
    #pragma unroll
    for (int mt = 0; mt < 4; ++mt)
        #pragma unroll
        for (int nt = 0; nt < 4; ++nt) acc[mt][nt] = fz;
    {
        bf16x8 a2[4], b2[4];
        #pragma unroll
        for (int mt = 0; mt < 4; ++mt) {
            int s = s0 + wm * 64 + mt * 16 + ln;
            Bf8 az;
            az.v = *(const bf16x8*)(attb + ((size_t)h * MPAD + s) * 16 + (quad & 1) * 8);
            if (quad >= 2) {
                #pragma unroll
                for (int j = 0; j < 8; ++j) az.us[j] = 0;
            }
            a2[mt] = az.v;
        }
        #pragma unroll
        for (int nt = 0; nt < 4; ++nt) {
            int f = wn * 64 + nt * 16 + ln;
            b2[nt] = *(const bf16x8*)(h1T + ((size_t)(h * F_N + f)) * 32 + quad * 8);
        }
        #pragma unroll
        for (int mt = 0; mt < 4; ++mt)
            #pragma unroll
            for (int nt = 0; nt < 4; ++nt)
                acc[mt][nt] = __builtin_amdgcn_mfma_f32_16x16x32_bf16(a2[mt], b2[nt], acc[mt][nt], 0, 0, 0);
    }
    #pragma unroll
    for (int it = 0; it < 4; ++it) {
        int kk = it * 32;
        bf16x8 af[4], bfr[4];
        #pragma unroll
        for (int mt = 0; mt < 4; ++mt)
            af[mt] = *(const bf16x8*)(Tb + (size_t)(s0 + wm * 64 + mt * 16 + ln) * F_N + kk + quad * 8);
        #pragma unroll
        for (int nt = 0; nt < 4; ++nt)
            bfr[nt] = *(const bf16x8*)(W2T + (size_t)(h * F_N + wn * 64 + nt * 16 + ln) * F_N + kk + quad * 8);
        #pragma unroll
        for (int mt = 0; mt < 4; ++mt)
            #pragma unroll
            for (int nt = 0; nt < 4; ++nt)
                acc[mt][nt] = __builtin_amdgcn_mfma_f32_16x16x32_bf16(af[mt], bfr[nt], acc[mt][nt], 0, 0, 0);
    }
    __shared__ float lsum[128], lsq[128];
    if (t < 128) { lsum[t] = 0.0f; lsq[t] = 0.0f; }
    __syncthreads();
    #pragma unroll
    for (int nt = 0; nt < 4; ++nt) {
        int f = wn * 64 + nt * 16 + ln;
        float p1 = 0.0f, p2 = 0.0f;
        #pragma unroll
        for (int mt = 0; mt < 4; ++mt) {
            int sb = s0 + wm * 64 + mt * 16 + quad * 4;
            #pragma unroll
            for (int r = 0; r < 4; ++r) {
                float val = acc[mt][nt][r];
                P[((size_t)h * MPAD + sb + r) * F_N + f] = val;
                p1 += val; p2 += val * val;
            }
        }
        atomicAdd(&lsum[f], p1);
        atomicAdd(&lsq[f], p2);
    }
    __syncthreads();
    if (t < 128) {
        atomicAdd(&usum[h * F_N + t], lsum[t]);
        atomicAdd(&usq[h * F_N + t], lsq[t]);
    }
}

// ---------------- G4: fused bn-finalize + G=elu(u@v^T) + final GAT layer + log_softmax ------
__global__ __launch_bounds__(256) void g_out(const float* __restrict__ P,
        const float* __restrict__ usum, const float* __restrict__ usq, const float* __restrict__ Mg,
        const float* __restrict__ g1, const float* __restrict__ b1,
        const float* __restrict__ g2, const float* __restrict__ b2,
        const float* __restrict__ outW, const int* __restrict__ inter, float* __restrict__ out) {
    const int t = threadIdx.x, l = t & 63, w = t >> 6, quad = l >> 4, ln = l & 15;
    const int s0 = blockIdx.x * 64;
    __shared__ __bf16 v_lds[64 * 136];   // [h*16+r][f]
    __shared__ float G_lds[64 * 68];     // [s_local][h*16+r]
    __shared__ float scs[512], shs[512];
    __shared__ float W_lds[1024];
    for (int i = t; i < 1024; i += 256) W_lds[i] = outW[i];
    if (t < 128) {
        #pragma unroll
        for (int h = 0; h < 4; ++h) {
            int i = h * F_N + t;
            float mean = usum[i] * (1.0f / S_N);
            float var = usq[i] * (1.0f / S_N) - mean * mean;
            float sc = g2[i] * rsqrtf(var + 1e-5f);
            scs[i] = sc;
            shs[i] = b2[i] - mean * sc;
        }
    }
    {   // v = lrelu(bn1(M)); thread t: f = t&127, heads (t>>7)*2 .. +1
        int f = t & 127;
        int hb = (t >> 7) * 2;
        #pragma unroll
        for (int hh = hb; hh < hb + 2; ++hh) {
            float mv[16], s1 = 0.0f, s2 = 0.0f;
            #pragma unroll
            for (int r = 0; r < 16; ++r) {
                mv[r] = Mg[(hh * 16 + r) * F_N + f];
                s1 += mv[r]; s2 += mv[r] * mv[r];
            }
            float m1 = s1 * 0.0625f, v1 = s2 * 0.0625f - m1 * m1;
            int i = hh * F_N + f;
            float g = g1[i] * rsqrtf(v1 + 1e-5f);
            float bb = b1[i] - m1 * g;
            #pragma unroll
            for (int r = 0; r < 16; ++r)
                v_lds[(hh * 16 + r) * 136 + f] = (__bf16)lrelu02(mv[r] * g + bb);
        }
    }
    __syncthreads();
    // wave w = head h: G tile 64 rows x 16 cols
    const int h = w;
    const f32x4 fz = {0.0f, 0.0f, 0.0f, 0.0f};
    #pragma unroll
    for (int mt = 0; mt < 4; ++mt) {
        f32x4 gacc = fz;
        int s = s0 + mt * 16 + ln;
        #pragma unroll
        for (int kit = 0; kit < 4; ++kit) {
            int k0 = kit * 32 + quad * 8;
            const float* pp = P + ((size_t)h * MPAD + s) * F_N + k0;
            f32x4 p0 = *(const f32x4*)pp;
            f32x4 p1 = *(const f32x4*)(pp + 4);
            f32x4 c0 = *(const f32x4*)(scs + h * F_N + k0);
            f32x4 c1 = *(const f32x4*)(scs + h * F_N + k0 + 4);
            f32x4 d0 = *(const f32x4*)(shs + h * F_N + k0);
            f32x4 d1 = *(const f32x4*)(shs + h * F_N + k0 + 4);
            Bh8 af;
            #pragma unroll
            for (int j = 0; j < 4; ++j) {
                af.h[j]     = (__bf16)lrelu02(p0[j] * c0[j] + d0[j]);
                af.h[j + 4] = (__bf16)lrelu02(p1[j] * c1[j] + d1[j]);
            }
            bf16x8 bv = *(const bf16x8*)(&v_lds[(h * 16 + ln) * 136 + k0]);
            gacc = __builtin_amdgcn_mfma_f32_16x16x32_bf16(af.v, bv, gacc, 0, 0, 0);
        }
        #pragma unroll
        for (int r = 0; r < 4; ++r)
            G_lds[(mt * 16 + quad * 4 + r) * 68 + h * 16 + ln] = eluf(gacc[r]);
    }
    __syncthreads();
    // final layer: out[s][c]
    const int c = t & 15, ss = t >> 4;
    #pragma unroll
    for (int pass = 0; pass < 4; ++pass) {
        int sl = pass * 16 + ss;
        int s = s0 + sl;
        float hm = 0.0f;
        #pragma unroll
        for (int j = 0; j < 64; ++j) hm += G_lds[sl * 68 + j] * W_lds[j * 16 + c];
        int valid = s < S_N;
        int msk = valid ? (inter[(valid ? s : 0) * 16 + c] > 0) : 0;
        int cn = msk;
        #pragma unroll
        for (int m = 8; m > 0; m >>= 1) cn += __shfl_xor(cn, m, 16);
        float attf = cn > 0 ? (msk ? 1.0f / (float)cn : 0.0f) : 0.0625f;
        float y = eluf(eluf(attf * hm));
        float mx = y;
        #pragma unroll
        for (int m = 8; m > 0; m >>= 1) mx = fmaxf(mx, __shfl_xor(mx, m, 16));
        float ex = expf(y - mx);
        float sm = ex;
        #pragma unroll
        for (int m = 8; m > 0; m >>= 1) sm += __shfl_xor(sm, m, 16);
        if (valid) out[s * 16 + c] = y - mx - logf(sm);
    }
}

extern "C" void kernel_launch(void* const* d_in, const int* in_sizes, int n_in,
                              void* d_out, int out_size, void* d_ws, size_t ws_size,
                              hipStream_t stream) {
    const int* inter = (const int*)d_in[0];
    const int* city  = (const int*)d_in[1];
    const int* prov  = (const int*)d_in[2];
    const int* src   = (const int*)d_in[3];
    const float* Sfeat = (const float*)d_in[4];
    const float* Rfeat = (const float*)d_in[5];
    const float* W1 = (const float*)d_in[6];
    const float* W2 = (const float*)d_in[7];
    const float* a  = (const float*)d_in[8];
    const float* g1 = (const float*)d_in[11];
    const float* b1 = (const float*)d_in[12];
    const float* g2 = (const float*)d_in[13];
    const float* b2 = (const float*)d_in[14];
    const float* outW = (const float*)d_in[15];
    float* out = (float*)d_out;

    char* p = (char*)d_ws;
    // ---- zeroed region ----
    float* M    = (float*)p; p += 4 * 16 * F_N * 4;   // 32768
    float* usum = (float*)p; p += 2048;
    float* usq  = (float*)p; p += 2048;
    u32*   cc   = (u32*)p;   p += 8192;
    u32*   pc   = (u32*)p;   p += 8192;
    size_t zbytes = (size_t)(p - (char*)d_ws);        // 53248
    // ---- rest ----
    u64* tcity = (u64*)p; p += 32 * (size_t)MPAD * 8;
    u64* tprov = (u64*)p; p += 32 * (size_t)MPAD * 8;
    __bf16* YT  = (__bf16*)p; p += (size_t)F_N * B_N * 2;
    __bf16* ZT  = (__bf16*)p; p += (size_t)F_N * B_N * 2;
    __bf16* SfB = (__bf16*)p; p += (size_t)MPAD * F_N * 2;
    __bf16* W2T = (__bf16*)p; p += 512 * 128 * 2;
    __bf16* h1T = (__bf16*)p; p += 4 * 128 * 32 * 2;
    float*  q   = (float*)p;  p += 512;
    float*  Tp  = (float*)p;  p += 4 * (size_t)MPAD * F_N * 4;
    __bf16* Tb  = (__bf16*)p; p += (size_t)MPAD * F_N * 2;
    __bf16* attb= (__bf16*)p; p += 4 * (size_t)MPAD * 16 * 2;
    float*  P   = (float*)p;  p += 4 * (size_t)MPAD * F_N * 4;

    hipMemsetAsync(d_ws, 0, zbytes, stream);
    k_bits_pre<<<6656, 256, 0, stream>>>(city, prov, src, Sfeat, Rfeat, W1, W2, a,
                                         tcity, tprov, cc, pc, SfB, W2T, h1T, q);
    k_yz      <<<1024, 256, 0, stream>>>(Sfeat, src, cc, pc, YT, ZT);
    g_T       <<<dim3(79, 4), 256, 0, stream>>>(YT, ZT, tcity, tprov, Tp);
    k_tred    <<<1264, 256, 0, stream>>>(Tp, Tb);
    g_h2attM  <<<dim3(79, 4), 256, 0, stream>>>(SfB, W2T, a, q, inter, attb, M);
    g_P       <<<dim3(79, 4), 256, 0, stream>>>(Tb, W2T, attb, h1T, P, usum, usq);
    g_out     <<<157, 256, 0, stream>>>(P, usum, usq, M, g1, b1, g2, b2, outW, inter, out);
}